// Round 3
// baseline (435.697 us; speedup 1.0000x reference)
//
#include <hip/hip_runtime.h>
#include <math.h>

#define T_LEN   1024
#define D_DIM   512
#define B_DIM   16
#define OUT_T   1280
#define K_SEL   16
#define NCAND   20
#define NSER    (B_DIM * D_DIM)   /* 8192 series */

// d_ws layout:
//   [0, 16384)     double2 twd[1024]  e^{-2pi i m/1024} fp64 (cos, -sin)
//   [16384, 24576) float2  twf[1024]  e^{+2pi i m/1024} fp32 (cos, +sin)  [recon]
//   [24576, 32768) float2  twn[1024]  e^{-2pi i m/1024} fp32 (cos, -sin)  [dft]
//   [32768, +2MiB) float4  sel[8192][16]  (k, re*2/N, im*2/N, 0)
//
// d_out doubles as scratch for xT (16,512,1024) fp32 = 32 MB; fully
// overwritten by k_recon at the end.

// ---------------- kernel 0: twiddle tables ----------------
__global__ void k_tables(double2* __restrict__ twd, float2* __restrict__ twf,
                         float2* __restrict__ twn) {
    int m = blockIdx.x * blockDim.x + threadIdx.x;
    if (m >= T_LEN) return;
    const double w0 = 6.283185307179586476925286766559e0 / (double)T_LEN;
    double s, c;
    sincos(w0 * (double)m, &s, &c);
    twd[m] = make_double2(c, -s);               // e^{-i theta} fp64
    twf[m] = make_float2((float)c, (float)s);   // e^{+i theta} fp32
    twn[m] = make_float2((float)c, (float)-s);  // e^{-i theta} fp32
}

// ---------------- kernel T: transpose x(b,t,d) -> xT(b,d,t) ----------------
__global__ __launch_bounds__(256) void k_transpose(const float* __restrict__ x,
                                                   float* __restrict__ xT) {
    __shared__ float tile[32][33];
    int blk = blockIdx.x;            // b(16) * ttile(32) * dtile(16) = 8192
    int b  = blk >> 9;
    int tt = (blk >> 4) & 31;
    int dt = blk & 15;
    int t0 = tt * 32, d0 = dt * 32;
    int lr = threadIdx.x >> 5;       // 0..7
    int lc = threadIdx.x & 31;       // 0..31
    const float* xb = x + (size_t)b * T_LEN * D_DIM;
#pragma unroll
    for (int i = 0; i < 4; i++) {
        int row = lr + i * 8;
        tile[row][lc] = xb[(size_t)(t0 + row) * D_DIM + (d0 + lc)];
    }
    __syncthreads();
    float* xTb = xT + (size_t)b * D_DIM * T_LEN;
#pragma unroll
    for (int i = 0; i < 4; i++) {
        int row = lr + i * 8;        // d-row within tile
        xTb[(size_t)(d0 + row) * T_LEN + (t0 + lc)] = tile[lc][row];
    }
}

// ------- kernel 1: fp32 DFT (32x32 CT, table twiddles) + top-20 + fp64 refine -------
__global__ __launch_bounds__(256, 4) void k_dft_topk(const float* __restrict__ xT,
                                                     const double2* __restrict__ twd,
                                                     const float2* __restrict__ twn,
                                                     float4* __restrict__ sel) {
    int s   = blockIdx.x;            // series id = b*512 + d
    int tid = threadIdx.x;

    __shared__ float   xs[T_LEN];            // 4 KB
    __shared__ float2  zs[32][33];           // 8.4 KB  z[k1][t0] = y*W1024^{k1 t0}
    __shared__ float2  w32s[32];             // 256 B   e^{-2pi i m/32}
    __shared__ float2  twl[T_LEN];           // 8 KB    e^{-2pi i m/1024} fp32
    __shared__ unsigned long long keyz[512]; // 4 KB    (mag_bits<<32)|(511-k)
    __shared__ unsigned long long redz[4];
    __shared__ int     candk[NCAND];
    __shared__ double2 candc[NCAND];

    // load series + tables (coalesced)
    const float* xp = xT + (size_t)s * T_LEN;
#pragma unroll
    for (int i = 0; i < 4; i++) xs[tid + 256 * i] = xp[tid + 256 * i];
#pragma unroll
    for (int i = 0; i < 4; i++) twl[tid + 256 * i] = twn[tid + 256 * i];
    if (tid < 32) w32s[tid] = twn[tid * 32];
    __syncthreads();

    // ---- phase A: y[k1][t0] = sum_t1 x[32 t1 + t0] W32^{k1 t1};  z = y*W1024^{k1 t0}
    int k1  = tid & 31;
    int t0b = (tid >> 5) << 2;       // this thread owns t0b..t0b+3
    {
        float yr0=0,yi0=0,yr1=0,yi1=0,yr2=0,yi2=0,yr3=0,yi3=0;
#pragma unroll
        for (int t1 = 0; t1 < 32; t1++) {
            const float4 xq = *(const float4*)&xs[32 * t1 + t0b];
            float2 w = w32s[(k1 * t1) & 31];
            yr0 += xq.x * w.x; yi0 += xq.x * w.y;
            yr1 += xq.y * w.x; yi1 += xq.y * w.y;
            yr2 += xq.z * w.x; yi2 += xq.z * w.y;
            yr3 += xq.w * w.x; yi3 += xq.w * w.y;
        }
        float yrA[4] = {yr0, yr1, yr2, yr3};
        float yiA[4] = {yi0, yi1, yi2, yi3};
#pragma unroll
        for (int i = 0; i < 4; i++) {
            int t0 = t0b + i;
            float2 tw = twl[(k1 * t0) & (T_LEN - 1)];
            zs[k1][t0] = make_float2(yrA[i] * tw.x - yiA[i] * tw.y,
                                     yrA[i] * tw.y + yiA[i] * tw.x);
        }
    }
    __syncthreads();

    // ---- phase B: c_k = sum_t0 z[k&31][t0] W32^{(k>>5) t0};  key = mag|k
#pragma unroll
    for (int kk = 0; kk < 2; kk++) {
        int k   = tid + kk * 256;
        int kb1 = k & 31, k0 = k >> 5;
        float cr = 0.f, ci = 0.f;
#pragma unroll
        for (int t0 = 0; t0 < 32; t0++) {
            float2 z = zs[kb1][t0];
            float2 w = w32s[(k0 * t0) & 31];
            cr += z.x * w.x - z.y * w.y;
            ci += z.x * w.y + z.y * w.x;
        }
        float mag = cr * cr + ci * ci;
        unsigned long long key = (k == 0) ? 0ull
            : (((unsigned long long)__float_as_uint(mag) << 32)
               | (unsigned)(511 - k));
        keyz[k] = key;
    }
    __syncthreads();

    // ---- top-NCAND candidates (uint64 key argmax; tie -> lower k) ----
    for (int r = 0; r < NCAND; r++) {
        unsigned long long a = keyz[tid], b2 = keyz[tid + 256];
        unsigned long long best = a > b2 ? a : b2;
#pragma unroll
        for (int off = 1; off <= 32; off <<= 1) {
            unsigned long long o = __shfl_xor(best, off);
            if (o > best) best = o;
        }
        if ((tid & 63) == 0) redz[tid >> 6] = best;
        __syncthreads();
        if (tid == 0) {
            unsigned long long bb = redz[0];
#pragma unroll
            for (int j = 1; j < 4; j++) if (redz[j] > bb) bb = redz[j];
            int bk = 511 - (int)(bb & 0xffffffffull);
            keyz[bk] = 0ull;         // mark taken
            candk[r] = bk;
        }
        __syncthreads();
    }

    // ---- fp64 refinement: exact 1024-term DFT per candidate (wave-parallel) ----
    {
        int w = tid >> 6, lane = tid & 63;
#pragma unroll
        for (int j = 0; j < 5; j++) {
            int c = w + 4 * j;       // covers 0..19
            int k = candk[c];
            double cr = 0.0, ci = 0.0;
#pragma unroll
            for (int i = 0; i < 16; i++) {
                int t = lane + 64 * i;
                double  xv = (double)xs[t];
                double2 tw = twd[(k * t) & (T_LEN - 1)];
                cr += xv * tw.x; ci += xv * tw.y;
            }
#pragma unroll
            for (int off = 1; off <= 32; off <<= 1) {
                cr += __shfl_xor(cr, off);
                ci += __shfl_xor(ci, off);
            }
            if (lane == 0) candc[c] = make_double2(cr, ci);
        }
    }
    __syncthreads();

    // ---- final: top-16 of 20 refined (fp64 mag, tie -> lower k), wave 0 ----
    if (tid < 64) {
        double m = -1.0; int k = 1 << 20; float re = 0.f, im = 0.f;
        if (tid < NCAND) {
            double2 d2 = candc[tid]; k = candk[tid];
            m = d2.x * d2.x + d2.y * d2.y;
            const double sc = 2.0 / (double)T_LEN;
            re = (float)(d2.x * sc); im = (float)(d2.y * sc);
        }
        for (int r = 0; r < K_SEL; r++) {
            double bm = m; int bk = k, bl = tid;
#pragma unroll
            for (int off = 1; off <= 32; off <<= 1) {
                double om = __shfl_xor(bm, off);
                int    ok = __shfl_xor(bk, off);
                int    ol = __shfl_xor(bl, off);
                if (om > bm || (om == bm && ok < bk)) { bm = om; bk = ok; bl = ol; }
            }
            float rre = __shfl(re, bl);
            float rim = __shfl(im, bl);
            if (tid == 0)
                sel[(size_t)s * K_SEL + r] = make_float4((float)bk, rre, rim, 0.f);
            if (tid == bl) m = -1.0;   // remove winner
        }
    }
}

// ---------------- kernel 2: sparse inverse reconstruction ----------------
__global__ __launch_bounds__(256) void k_recon(const float4* __restrict__ sel,
                                               const float2* __restrict__ twf,
                                               float* __restrict__ out) {
    int blk = blockIdx.x;            // b(16) * dblk(8) * tchunk(4) = 512
    int b    = blk >> 5;
    int dblk = (blk >> 2) & 7;
    int tc   = blk & 3;
    int tid  = threadIdx.x;
    int dd   = tid & 63;             // d within 64-wide tile
    int tg   = tid >> 6;             // 0..3 time-phase

    __shared__ float4 ssel[64][17];  // padded
    __shared__ float2 vt[T_LEN];     // V^m table, 8 KB

#pragma unroll
    for (int i = 0; i < 4; i++) vt[tid + 256 * i] = twf[tid + 256 * i];
    int d0 = dblk * 64;
#pragma unroll
    for (int i = 0; i < 4; i++) {
        int l = tid + 256 * i;       // 1024 entries = 64 series * 16
        int sdd = l >> 4, j = l & 15;
        ssel[sdd][j] = sel[((size_t)(b * D_DIM + d0 + sdd)) * K_SEL + j];
    }
    __syncthreads();

    int tstart = tc * 256 + tg;
    float zr[16], zi[16], sr[16], si[16];
#pragma unroll
    for (int j = 0; j < 16; j++) {
        float4 e = ssel[dd][j];
        int k = (int)e.x;
        float2 v0 = vt[(k * tstart) & (T_LEN - 1)];
        zr[j] = e.y * v0.x - e.z * v0.y;   // z = c * V^{k*tstart}
        zi[j] = e.y * v0.y + e.z * v0.x;
        float2 st = vt[(k * 4) & (T_LEN - 1)];
        sr[j] = st.x; si[j] = st.y;        // step V^{4k}
    }

    float* ob = out + (size_t)b * OUT_T * D_DIM + (d0 + dd);
    for (int it = 0; it < 64; it++) {
        int t = tstart + it * 4;
        float v = 0.0f;
#pragma unroll
        for (int j = 0; j < 16; j++) {
            v += zr[j];
            float nr = zr[j] * sr[j] - zi[j] * si[j];
            float ni = zr[j] * si[j] + zi[j] * sr[j];
            zr[j] = nr; zi[j] = ni;
        }
        ob[(size_t)t * D_DIM] = v;
        if (t < OUT_T - T_LEN)               // replicate t+1024 (periodicity)
            ob[(size_t)(t + T_LEN) * D_DIM] = v;
    }
}

// ---------------- launch ----------------
extern "C" void kernel_launch(void* const* d_in, const int* in_sizes, int n_in,
                              void* d_out, int out_size, void* d_ws, size_t ws_size,
                              hipStream_t stream) {
    (void)in_sizes; (void)n_in; (void)out_size; (void)ws_size;
    const float* x = (const float*)d_in[0];
    float* out = (float*)d_out;
    char* ws = (char*)d_ws;

    double2* twd = (double2*)ws;
    float2*  twf = (float2*)(ws + 16384);
    float2*  twn = (float2*)(ws + 24576);
    float4*  sel = (float4*)(ws + 32768);
    float*   xT  = out;   // reuse output buffer as transpose scratch (32MB < 40MB)

    hipLaunchKernelGGL(k_tables,    dim3(4),    dim3(256), 0, stream, twd, twf, twn);
    hipLaunchKernelGGL(k_transpose, dim3(8192), dim3(256), 0, stream, x, xT);
    hipLaunchKernelGGL(k_dft_topk,  dim3(8192), dim3(256), 0, stream, xT, twd, twn, sel);
    hipLaunchKernelGGL(k_recon,     dim3(512),  dim3(256), 0, stream, sel, twf, out);
}